// Round 1
// baseline (21996.817 us; speedup 1.0000x reference)
//
#include <hip/hip_runtime.h>
#include <math.h>

#define BSZ 64
#define PLEN 128
#define HLEN 64
#define EDIM 300
#define HDIM 512
#define G4 2048   // 4*HDIM
#define NCLS 3

__device__ __forceinline__ float sigf(float x) { return 1.0f / (1.0f + __expf(-x)); }
__device__ __forceinline__ float tanhfast(float x) { return 1.0f - 2.0f / (__expf(2.0f * x) + 1.0f); }

// ---------------------------------------------------------------------------
// zero small state buffers
__global__ __launch_bounds__(256) void zero_kernel(float* p, int n) {
    int i = blockIdx.x * 256 + threadIdx.x;
    if (i < n) p[i] = 0.0f;
}

// ---------------------------------------------------------------------------
// input projection: out[m][row] = emb[toks[m]] . Wih[row] + bih[row] + bhh[row]
// grid: (M/16, G4/16), block 256. tx = row-in-tile(16), ty = token-in-tile(16)
__global__ __launch_bounds__(256) void proj_kernel(
    const int* __restrict__ toks, const float* __restrict__ emb,
    const float* __restrict__ Wih, const float* __restrict__ bih,
    const float* __restrict__ bhh, float* __restrict__ out)
{
    __shared__ float es[16][EDIM];   // 16 tokens x 300 (row = 1200B, 16B aligned)
    int m0 = blockIdx.x * 16;
    int r0 = blockIdx.y * 16;
    int tid = threadIdx.x;
    // load 16 embedding rows: 1200 float4
    for (int i = tid; i < 16 * 75; i += 256) {
        int tok = i / 75, k4 = i % 75;
        int idx = toks[m0 + tok];
        ((float4*)&es[tok][0])[k4] = ((const float4*)(emb + (size_t)idx * EDIM))[k4];
    }
    __syncthreads();
    int tx = tid & 15, ty = tid >> 4;
    int row = r0 + tx;
    const float4* w = (const float4*)(Wih + (size_t)row * EDIM);
    const float4* x = (const float4*)&es[ty][0];
    float acc = 0.0f;
#pragma unroll 5
    for (int k = 0; k < 75; k++) {
        float4 a = x[k], b = w[k];
        acc += a.x * b.x + a.y * b.y + a.z * b.z + a.w * b.w;
    }
    out[(size_t)(m0 + ty) * G4 + row] = acc + bih[row] + bhh[row];
}

// ---------------------------------------------------------------------------
// one LSTM step. grid (4 batch-tiles, 32 unit-tiles), block 256.
// tx = unit-in-tile(16), ty = batch-in-tile(16)
__global__ __launch_bounds__(256) void lstm_step(
    const float* __restrict__ xproj,  // [B*T][2048], token m = b*T + t
    const float* __restrict__ Whh,    // [2048][512]
    const float* __restrict__ hin,    // [B][512]
    float* __restrict__ hout,         // [B][512]
    float* __restrict__ c,            // [B][512]
    float* __restrict__ outh,         // [B][T][512]
    int t, int T)
{
    __shared__ float hs[16][HDIM];
    int b0 = blockIdx.x * 16;
    int u0 = blockIdx.y * 16;
    int tid = threadIdx.x;
    for (int i = tid; i < 16 * 128; i += 256) {
        int bb = i >> 7, k4 = i & 127;
        ((float4*)&hs[bb][0])[k4] = ((const float4*)(hin + (size_t)(b0 + bb) * HDIM))[k4];
    }
    __syncthreads();
    int tx = tid & 15, ty = tid >> 4;
    int u = u0 + tx, b = b0 + ty;
    const float4* hv = (const float4*)&hs[ty][0];
    const float4* w0 = (const float4*)(Whh + (size_t)(0 * HDIM + u) * HDIM);
    const float4* w1 = (const float4*)(Whh + (size_t)(1 * HDIM + u) * HDIM);
    const float4* w2 = (const float4*)(Whh + (size_t)(2 * HDIM + u) * HDIM);
    const float4* w3 = (const float4*)(Whh + (size_t)(3 * HDIM + u) * HDIM);
    float a0 = 0.f, a1v = 0.f, a2v = 0.f, a3v = 0.f;
#pragma unroll 4
    for (int k = 0; k < 128; k++) {
        float4 x = hv[k];
        float4 y0 = w0[k]; a0  += x.x * y0.x + x.y * y0.y + x.z * y0.z + x.w * y0.w;
        float4 y1 = w1[k]; a1v += x.x * y1.x + x.y * y1.y + x.z * y1.z + x.w * y1.w;
        float4 y2 = w2[k]; a2v += x.x * y2.x + x.y * y2.y + x.z * y2.z + x.w * y2.w;
        float4 y3 = w3[k]; a3v += x.x * y3.x + x.y * y3.y + x.z * y3.z + x.w * y3.w;
    }
    size_t xbase = (size_t)(b * T + t) * G4 + u;
    a0  += xproj[xbase];
    a1v += xproj[xbase + 512];
    a2v += xproj[xbase + 1024];
    a3v += xproj[xbase + 1536];
    float ig = sigf(a0), fg = sigf(a1v), gg = tanhfast(a2v), og = sigf(a3v);
    size_t off = (size_t)b * HDIM + u;
    float cn = fg * c[off] + ig * gg;
    float hn = og * tanhfast(cn);
    c[off] = cn;
    hout[off] = hn;
    outh[(size_t)(b * T + t) * HDIM + u] = hn;
}

// ---------------------------------------------------------------------------
// a1[b][h][p] = sum_j Wy[h][j] * outp[b][p][j]
// grid (64, 32, 8): b, h-tile, p-tile. block 256: tx = p(16), ty = h(16)
__global__ __launch_bounds__(256) void a1_kernel(
    const float* __restrict__ Wy, const float* __restrict__ outp,
    float* __restrict__ a1)
{
    __shared__ float os[16][HDIM + 4];  // pad 4 -> stride 516 (2-way banks, free)
    int b = blockIdx.x, h0 = blockIdx.y * 16, p0 = blockIdx.z * 16;
    int tid = threadIdx.x;
    for (int i = tid; i < 16 * 128; i += 256) {
        int pp = i >> 7, k4 = i & 127;
        ((float4*)&os[pp][0])[k4] = ((const float4*)(outp + (size_t)(b * PLEN + p0 + pp) * HDIM))[k4];
    }
    __syncthreads();
    int tx = tid & 15, ty = tid >> 4;
    const float4* ov = (const float4*)&os[tx][0];
    const float4* w = (const float4*)(Wy + (size_t)(h0 + ty) * HDIM);
    float acc = 0.0f;
#pragma unroll 4
    for (int k = 0; k < 128; k++) {
        float4 a = ov[k], bb = w[k];
        acc += a.x * bb.x + a.y * bb.y + a.z * bb.z + a.w * bb.w;
    }
    a1[((size_t)b * HDIM + h0 + ty) * PLEN + p0 + tx] = acc;
}

// ---------------------------------------------------------------------------
// attention pre-step: a2 = q_t.Wh^T + r.Wr^T ; tt = tanh(r.Wt^T)
// grid (4, 32), block 256: tx = unit(16), ty = batch(16)
__global__ __launch_bounds__(256) void att_pre(
    const float* __restrict__ outh,  // [B][HLEN][512]
    const float* __restrict__ r,
    const float* __restrict__ Wh, const float* __restrict__ Wr,
    const float* __restrict__ Wt,
    float* __restrict__ a2, float* __restrict__ tt, int t)
{
    __shared__ float qs[16][HDIM];
    __shared__ float rs[16][HDIM];
    int b0 = blockIdx.x * 16, u0 = blockIdx.y * 16;
    int tid = threadIdx.x;
    for (int i = tid; i < 16 * 128; i += 256) {
        int bb = i >> 7, k4 = i & 127;
        ((float4*)&qs[bb][0])[k4] = ((const float4*)(outh + (size_t)((b0 + bb) * HLEN + t) * HDIM))[k4];
        ((float4*)&rs[bb][0])[k4] = ((const float4*)(r + (size_t)(b0 + bb) * HDIM))[k4];
    }
    __syncthreads();
    int tx = tid & 15, ty = tid >> 4;
    int u = u0 + tx, b = b0 + ty;
    const float4* q4 = (const float4*)&qs[ty][0];
    const float4* r4 = (const float4*)&rs[ty][0];
    const float4* wh = (const float4*)(Wh + (size_t)u * HDIM);
    const float4* wr = (const float4*)(Wr + (size_t)u * HDIM);
    const float4* wt = (const float4*)(Wt + (size_t)u * HDIM);
    float ah = 0.f, ar = 0.f, at = 0.f;
#pragma unroll 4
    for (int k = 0; k < 128; k++) {
        float4 qq = q4[k], rr = r4[k];
        float4 a = wh[k]; ah += qq.x * a.x + qq.y * a.y + qq.z * a.z + qq.w * a.w;
        float4 b2 = wr[k]; ar += rr.x * b2.x + rr.y * b2.y + rr.z * b2.z + rr.w * b2.w;
        float4 c2 = wt[k]; at += rr.x * c2.x + rr.y * c2.y + rr.z * c2.z + rr.w * c2.w;
    }
    a2[(size_t)b * HDIM + u] = ah + ar;
    tt[(size_t)b * HDIM + u] = tanhfast(at);
}

// ---------------------------------------------------------------------------
// attention step: s[b][p] = sum_h wv[h]*tanh(a1[b][h][p]+a2[b][h]);
// softmax over p; r[b] = sum_p outp[b][p][:]*score[p] + tt[b]
// grid 64 (one block per batch), block 256
__global__ __launch_bounds__(256) void att_step(
    const float* __restrict__ a1,    // [B][512][128]
    const float* __restrict__ a2,    // [B][512]
    const float* __restrict__ tt,    // [B][512]
    const float* __restrict__ wv,    // [512]
    const float* __restrict__ outp,  // [B][PLEN][512]
    float* __restrict__ r)
{
    int b = blockIdx.x;
    int tid = threadIdx.x;
    __shared__ float sc[PLEN];
    __shared__ float part[256];
    int p = tid & 127, half = tid >> 7;
    const float* a1b = a1 + (size_t)b * HDIM * PLEN;
    const float* a2b = a2 + (size_t)b * HDIM;
    float s = 0.0f;
    int h0 = half * 256;
    for (int h = h0; h < h0 + 256; h++) {
        s += wv[h] * tanhfast(a1b[(size_t)h * PLEN + p] + a2b[h]);
    }
    part[tid] = s;
    __syncthreads();
    if (tid < 128) sc[tid] = part[tid] + part[tid + 128];
    __syncthreads();
    if (tid < 64) {
        float v0 = sc[tid], v1 = sc[tid + 64];
        float m = fmaxf(v0, v1);
        for (int off = 32; off; off >>= 1) m = fmaxf(m, __shfl_xor(m, off));
        float e0 = __expf(v0 - m), e1 = __expf(v1 - m);
        float ssum = e0 + e1;
        for (int off = 32; off; off >>= 1) ssum += __shfl_xor(ssum, off);
        float inv = 1.0f / ssum;
        sc[tid] = e0 * inv;
        sc[tid + 64] = e1 * inv;
    }
    __syncthreads();
    const float* opb = outp + (size_t)b * PLEN * HDIM;
    for (int uu = tid; uu < HDIM; uu += 256) {
        float acc = 0.0f;
        for (int pp = 0; pp < PLEN; pp++) acc += sc[pp] * opb[(size_t)pp * HDIM + uu];
        r[(size_t)b * HDIM + uu] = acc + tt[(size_t)b * HDIM + uu];
    }
}

// ---------------------------------------------------------------------------
// final: rep = tanh(r.fc1^T + b1 + hn.fc2^T + b2); out = rep.fc3^T + b3
// grid 64 (per batch), block 256
__global__ __launch_bounds__(256) void final_kernel(
    const float* __restrict__ r, const float* __restrict__ hn,
    const float* __restrict__ fc1w, const float* __restrict__ fc1b,
    const float* __restrict__ fc2w, const float* __restrict__ fc2b,
    const float* __restrict__ fc3w, const float* __restrict__ fc3b,
    float* __restrict__ out)
{
    int b = blockIdx.x, tid = threadIdx.x;
    __shared__ float rs[HDIM], hs[HDIM], rep[HDIM], red[256];
    for (int i = tid; i < 128; i += 256) {
        ((float4*)rs)[i] = ((const float4*)(r + (size_t)b * HDIM))[i];
        ((float4*)hs)[i] = ((const float4*)(hn + (size_t)b * HDIM))[i];
    }
    __syncthreads();
    for (int u = tid; u < HDIM; u += 256) {
        const float4* w1 = (const float4*)(fc1w + (size_t)u * HDIM);
        const float4* w2 = (const float4*)(fc2w + (size_t)u * HDIM);
        float a = 0.f, bacc = 0.f;
        for (int k = 0; k < 128; k++) {
            float4 rv = ((float4*)rs)[k], hv = ((float4*)hs)[k];
            float4 x = w1[k]; a    += rv.x * x.x + rv.y * x.y + rv.z * x.z + rv.w * x.w;
            float4 y = w2[k]; bacc += hv.x * y.x + hv.y * y.y + hv.z * y.z + hv.w * y.w;
        }
        rep[u] = tanhfast(a + fc1b[u] + bacc + fc2b[u]);
    }
    __syncthreads();
    for (int cix = 0; cix < NCLS; cix++) {
        red[tid] = rep[tid] * fc3w[(size_t)cix * HDIM + tid]
                 + rep[tid + 256] * fc3w[(size_t)cix * HDIM + tid + 256];
        __syncthreads();
        for (int off = 128; off; off >>= 1) {
            if (tid < off) red[tid] += red[tid + off];
            __syncthreads();
        }
        if (tid == 0) out[b * NCLS + cix] = red[0] + fc3b[cix];
        __syncthreads();
    }
}

// ---------------------------------------------------------------------------
extern "C" void kernel_launch(void* const* d_in, const int* in_sizes, int n_in,
                              void* d_out, int out_size, void* d_ws, size_t ws_size,
                              hipStream_t stream)
{
    const int*   premise = (const int*)d_in[0];
    const int*   hyp     = (const int*)d_in[1];
    const float* emb     = (const float*)d_in[2];
    const float* Wih1    = (const float*)d_in[3];
    const float* Whh1    = (const float*)d_in[4];
    const float* bih1    = (const float*)d_in[5];
    const float* bhh1    = (const float*)d_in[6];
    const float* Wih2    = (const float*)d_in[7];
    const float* Whh2    = (const float*)d_in[8];
    const float* bih2    = (const float*)d_in[9];
    const float* bhh2    = (const float*)d_in[10];
    const float* Wy      = (const float*)d_in[11];
    const float* Wh      = (const float*)d_in[12];
    const float* Wr      = (const float*)d_in[13];
    const float* Wt      = (const float*)d_in[14];
    const float* wv      = (const float*)d_in[15];
    const float* fc1w    = (const float*)d_in[16];
    const float* fc1b    = (const float*)d_in[17];
    const float* fc2w    = (const float*)d_in[18];
    const float* fc2b    = (const float*)d_in[19];
    const float* fc3w    = (const float*)d_in[20];
    const float* fc3b    = (const float*)d_in[21];
    float* out = (float*)d_out;

    float* ws = (float*)d_ws;
    size_t off = 0;
    float* xp    = ws + off; off += (size_t)BSZ * PLEN * G4;    // 16.78M
    float* xh    = ws + off; off += (size_t)BSZ * HLEN * G4;    // 8.39M
    float* outp  = ws + off; off += (size_t)BSZ * PLEN * HDIM;  // 4.19M
    float* outh  = ws + off; off += (size_t)BSZ * HLEN * HDIM;  // 2.10M
    float* a1buf = ws + off; off += (size_t)BSZ * HDIM * PLEN;  // 4.19M
    float* smallbase = ws + off;
    float* hA   = ws + off; off += BSZ * HDIM;
    float* hB   = ws + off; off += BSZ * HDIM;
    float* cbuf = ws + off; off += BSZ * HDIM;
    float* h2A  = ws + off; off += BSZ * HDIM;
    float* h2B  = ws + off; off += BSZ * HDIM;
    float* a2b  = ws + off; off += BSZ * HDIM;
    float* ttb  = ws + off; off += BSZ * HDIM;
    float* rb   = ws + off; off += BSZ * HDIM;
    if (ws_size < off * sizeof(float)) return;  // workspace too small: fail loudly

    // zero h0/c0/r state (re-poisoned to 0xAA before every call)
    {
        int n = 8 * BSZ * HDIM;
        zero_kernel<<<dim3((n + 255) / 256), dim3(256), 0, stream>>>(smallbase, n);
    }

    // input projections (include both biases)
    proj_kernel<<<dim3(BSZ * PLEN / 16, G4 / 16), dim3(256), 0, stream>>>(premise, emb, Wih1, bih1, bhh1, xp);
    proj_kernel<<<dim3(BSZ * HLEN / 16, G4 / 16), dim3(256), 0, stream>>>(hyp, emb, Wih2, bih2, bhh2, xh);

    // premise LSTM (h0 = 0, c0 = 0)
    float* hin = hA;
    float* hout = hB;
    for (int t = 0; t < PLEN; t++) {
        lstm_step<<<dim3(4, 32), dim3(256), 0, stream>>>(xp, Whh1, hin, hout, cbuf, outp, t, PLEN);
        float* tmp = hin; hin = hout; hout = tmp;
    }

    // hypothesis LSTM (h0 = 0, c0 = c_p -> continue using cbuf)
    hin = h2A; hout = h2B;
    for (int t = 0; t < HLEN; t++) {
        lstm_step<<<dim3(4, 32), dim3(256), 0, stream>>>(xh, Whh2, hin, hout, cbuf, outh, t, HLEN);
        float* tmp = hin; hin = hout; hout = tmp;
    }
    float* hnh = hin;  // final hypothesis h

    // a1 = einsum('hj,bpj->bhp', Wy, outp)
    a1_kernel<<<dim3(BSZ, HDIM / 16, PLEN / 16), dim3(256), 0, stream>>>(Wy, outp, a1buf);

    // word-by-word attention recurrence
    for (int t = 0; t < HLEN; t++) {
        att_pre<<<dim3(4, 32), dim3(256), 0, stream>>>(outh, rb, Wh, Wr, Wt, a2b, ttb, t);
        att_step<<<dim3(BSZ), dim3(256), 0, stream>>>(a1buf, a2b, ttb, wv, outp, rb);
    }

    // final classifier
    final_kernel<<<dim3(BSZ), dim3(256), 0, stream>>>(rb, hnh, fc1w, fc1b, fc2w, fc2b, fc3w, fc3b, out);
}

// Round 3
// 16698.070 us; speedup vs baseline: 1.3173x; 1.3173x over previous
//
#include <hip/hip_runtime.h>
#include <math.h>

#define BSZ 64
#define PLEN 128
#define HLEN 64
#define EDIM 300
#define HDIM 512
#define G4 2048   // 4*HDIM
#define NCLS 3
#define NBLK 256  // persistent-kernel grid size (<= 256 CUs, co-resident)

__device__ __forceinline__ float sigf(float x) { return 1.0f / (1.0f + __expf(-x)); }
__device__ __forceinline__ float tanhfast(float x) { return 1.0f - 2.0f / (__expf(2.0f * x) + 1.0f); }

// ---------------------------------------------------------------------------
// software grid barrier (sense-reversing, device-scope). cnt/gen live in d_ws
// and are zeroed by bar_init each call (graph node -> re-zeroed every replay).
__device__ __forceinline__ void gbar(unsigned* cnt, unsigned* gen) {
    __syncthreads();   // drains this block's vmem ops (vmcnt(0) before s_barrier)
    if (threadIdx.x == 0) {
        __threadfence();  // device-scope release: L2 writeback covers block's stores
        unsigned g = __hip_atomic_load(gen, __ATOMIC_RELAXED, __HIP_MEMORY_SCOPE_AGENT);
        unsigned old = __hip_atomic_fetch_add(cnt, 1u, __ATOMIC_ACQ_REL, __HIP_MEMORY_SCOPE_AGENT);
        if (old == NBLK - 1u) {
            __hip_atomic_store(cnt, 0u, __ATOMIC_RELEASE, __HIP_MEMORY_SCOPE_AGENT);
            __hip_atomic_fetch_add(gen, 1u, __ATOMIC_RELEASE, __HIP_MEMORY_SCOPE_AGENT);
        } else {
            while (__hip_atomic_load(gen, __ATOMIC_RELAXED, __HIP_MEMORY_SCOPE_AGENT) == g)
                __builtin_amdgcn_s_sleep(2);
        }
        __threadfence();  // device-scope acquire: invalidate stale L1/L2 lines
    }
    __syncthreads();
}

__global__ __launch_bounds__(64) void bar_init(unsigned* bar) {
    bar[threadIdx.x] = 0u;
}

// ---------------------------------------------------------------------------
// input projection GEMM: out[m][row] = emb[toks[m]] . Wih[row] + bih[row]+bhh[row]
__global__ __launch_bounds__(256) void proj_kernel(
    const int* __restrict__ toks, const float* __restrict__ emb,
    const float* __restrict__ Wih, const float* __restrict__ bih,
    const float* __restrict__ bhh, float* __restrict__ out)
{
    __shared__ float es[16][EDIM];
    __shared__ float wsh[32][EDIM];
    int m0 = blockIdx.x * 16, r0 = blockIdx.y * 32;
    int tid = threadIdx.x;
    for (int i = tid; i < 16 * 75; i += 256) {
        int tk = i / 75, k4 = i % 75;
        ((float4*)&es[tk][0])[k4] = ((const float4*)(emb + (size_t)toks[m0 + tk] * EDIM))[k4];
    }
    for (int i = tid; i < 32 * 75; i += 256) {
        int r = i / 75, k4 = i % 75;
        ((float4*)&wsh[r][0])[k4] = ((const float4*)(Wih + (size_t)(r0 + r) * EDIM))[k4];
    }
    __syncthreads();
    int tx = tid & 31, ty = tid >> 5;
    const float4* w4 = (const float4*)&wsh[tx][0];
    const float4* e0 = (const float4*)&es[ty][0];
    const float4* e1 = (const float4*)&es[ty + 8][0];
    float a0 = 0.f, a1 = 0.f;
#pragma unroll 5
    for (int k = 0; k < 75; k++) {
        float4 w = w4[k];
        float4 x = e0[k]; a0 += x.x * w.x + x.y * w.y + x.z * w.z + x.w * w.w;
        float4 y = e1[k]; a1 += y.x * w.x + y.y * w.y + y.z * w.z + y.w * w.w;
    }
    float bsum = bih[r0 + tx] + bhh[r0 + tx];
    out[(size_t)(m0 + ty) * G4 + r0 + tx]     = a0 + bsum;
    out[(size_t)(m0 + ty + 8) * G4 + r0 + tx] = a1 + bsum;
}

// ---------------------------------------------------------------------------
// persistent LSTM: 128 premise + 64 hypothesis steps, software grid barrier.
// 256 blocks x 256 threads; block owns 2 units (8 gate rows) in LDS; c in LDS.
__global__ __launch_bounds__(256) void lstm_coop(
    const float* __restrict__ xp, const float* __restrict__ xh,
    const float* __restrict__ Whh1, const float* __restrict__ Whh2,
    float* __restrict__ outp, float* __restrict__ outh,
    float* __restrict__ hA, float* __restrict__ hB,
    unsigned* __restrict__ bar)
{
    unsigned* cnt = bar;
    unsigned* gen = bar + 16;
    __shared__ float wsm[8][516];
    __shared__ float hst[16][516];
    __shared__ float gsm[16][65];
    __shared__ float cst[128];
    int bk = blockIdx.x;
    int u0 = bk * 2;
    int tid = threadIdx.x;

    for (int i = tid; i < 8 * 128; i += 256) {
        int r = i >> 7, k4 = i & 127;
        int g = r >> 1, uu = r & 1;
        ((float4*)&wsm[r][0])[k4] =
            ((const float4*)(Whh1 + (size_t)(g * HDIM + u0 + uu) * HDIM))[k4];
    }
    if (tid < 128) cst[tid] = 0.0f;
    __syncthreads();

    int r = tid & 7, bl = (tid >> 3) & 15, kh = tid >> 7;

    for (int t = 0; t < PLEN + HLEN; t++) {
        int layer2 = (t >= PLEN);
        int tloc = layer2 ? t - PLEN : t;
        int T = layer2 ? HLEN : PLEN;
        const float* xproj = layer2 ? xh : xp;
        float* outseq = layer2 ? outh : outp;
        const float* hin = (t & 1) ? hB : hA;
        float* hout = (t & 1) ? hA : hB;
        bool hzero = (tloc == 0);

        if (t == PLEN) {   // switch to layer-2 weights (uniform branch)
            __syncthreads();
            for (int i = tid; i < 8 * 128; i += 256) {
                int rr = i >> 7, k4 = i & 127;
                int g = rr >> 1, uu = rr & 1;
                ((float4*)&wsm[rr][0])[k4] =
                    ((const float4*)(Whh2 + (size_t)(g * HDIM + u0 + uu) * HDIM))[k4];
            }
            __syncthreads();
        }

        if (!hzero) {
            for (int q = 0; q < 4; q++) {
                for (int i = tid; i < 16 * 128; i += 256) {
                    int bb = i >> 7, k4 = i & 127;
                    ((float4*)&hst[bb][0])[k4] =
                        ((const float4*)(hin + (size_t)(q * 16 + bb) * HDIM))[k4];
                }
                __syncthreads();
                const float4* wrow = (const float4*)&wsm[r][0] + kh * 64;
                const float4* hrow = (const float4*)&hst[bl][0] + kh * 64;
                float acc = 0.f;
#pragma unroll 8
                for (int k = 0; k < 64; k++) {
                    float4 a = wrow[k], b = hrow[k];
                    acc += a.x * b.x + a.y * b.y + a.z * b.z + a.w * b.w;
                }
                gsm[r + 8 * kh][q * 16 + bl] = acc;
                __syncthreads();
            }
        }
        if (tid < 128) {
            int b = tid & 63, uu = tid >> 6;
            float gi = 0.f, gf = 0.f, gg = 0.f, go = 0.f;
            if (!hzero) {
                gi = gsm[0 + uu][b] + gsm[8 + uu][b];
                gf = gsm[2 + uu][b] + gsm[10 + uu][b];
                gg = gsm[4 + uu][b] + gsm[12 + uu][b];
                go = gsm[6 + uu][b] + gsm[14 + uu][b];
            }
            size_t xb = ((size_t)b * T + tloc) * G4 + u0 + uu;
            gi += xproj[xb];
            gf += xproj[xb + 512];
            gg += xproj[xb + 1024];
            go += xproj[xb + 1536];
            float cn = sigf(gf) * cst[uu * 64 + b] + sigf(gi) * tanhfast(gg);
            float hn = sigf(go) * tanhfast(cn);
            cst[uu * 64 + b] = cn;
            hout[(size_t)b * HDIM + u0 + uu] = hn;
            outseq[((size_t)b * T + tloc) * HDIM + u0 + uu] = hn;
        }
        gbar(cnt, gen);
    }
}

// ---------------------------------------------------------------------------
// a1[b][h][p] = sum_j Wy[h][j] * outp[b][p][j]
__global__ __launch_bounds__(256) void a1_kernel(
    const float* __restrict__ Wy, const float* __restrict__ outp,
    float* __restrict__ a1)
{
    __shared__ float os[16][260];
    __shared__ float wsh[16][260];
    int b = blockIdx.x, h0 = blockIdx.y * 16, p0 = blockIdx.z * 16;
    int tid = threadIdx.x, tx = tid & 15, ty = tid >> 4;
    float acc = 0.f;
    for (int kc = 0; kc < 2; kc++) {
        __syncthreads();
        for (int i = tid; i < 16 * 64; i += 256) {
            int row = i >> 6, k4 = i & 63;
            ((float4*)&os[row][0])[k4] =
                ((const float4*)(outp + (size_t)(b * PLEN + p0 + row) * HDIM + kc * 256))[k4];
            ((float4*)&wsh[row][0])[k4] =
                ((const float4*)(Wy + (size_t)(h0 + row) * HDIM + kc * 256))[k4];
        }
        __syncthreads();
        const float4* ov = (const float4*)&os[tx][0];
        const float4* wv4 = (const float4*)&wsh[ty][0];
#pragma unroll 8
        for (int k = 0; k < 64; k++) {
            float4 a = ov[k], w = wv4[k];
            acc += a.x * w.x + a.y * w.y + a.z * w.z + a.w * w.w;
        }
    }
    a1[((size_t)b * HDIM + h0 + ty) * PLEN + p0 + tx] = acc;
}

// ---------------------------------------------------------------------------
// persistent attention: 64 steps x 3 phases, software grid barrier.
__global__ __launch_bounds__(256) void att_coop(
    const float* __restrict__ outh, float* __restrict__ rg,
    const float* __restrict__ a1b, float* __restrict__ a2g,
    float* __restrict__ ttg, float* __restrict__ sgb,
    const float* __restrict__ outp,
    const float* __restrict__ Wh, const float* __restrict__ Wr,
    const float* __restrict__ Wt, const float* __restrict__ wv,
    unsigned* __restrict__ bar)
{
    unsigned* cnt = bar;
    unsigned* gen = bar + 16;
    __shared__ float wmat[6][516];
    __shared__ float wvs[512];
    __shared__ float stq[8][516];
    __shared__ float str[8][516];
    __shared__ float gsa[32][9];
    __shared__ float sred[8][36];
    __shared__ float scb[128];
    __shared__ float rred[2][132];

    int bk = blockIdx.x;
    int u0 = bk * 2;
    int tid = threadIdx.x;

    for (int i = tid; i < 6 * 128; i += 256) {
        int rr = i >> 7, k4 = i & 127;
        int m = rr >> 1, uu = rr & 1;
        const float* W = (m == 0) ? Wh : ((m == 1) ? Wr : Wt);
        ((float4*)&wmat[rr][0])[k4] = ((const float4*)(W + (size_t)(u0 + uu) * HDIM))[k4];
    }
    for (int i = tid; i < 128; i += 256)
        ((float4*)wvs)[i] = ((const float4*)wv)[i];
    __syncthreads();

    int r8 = tid & 7, b3 = (tid >> 3) & 7, kq = tid >> 6;

    for (int t = 0; t < HLEN; t++) {
        // ---- phase A: a2 = q.Wh + r.Wr ; tt = tanh(r.Wt)
        for (int pass = 0; pass < 8; pass++) {
            int bp = pass * 8;
            for (int i = tid; i < 8 * 128; i += 256) {
                int row = i >> 7, k4 = i & 127;
                ((float4*)&stq[row][0])[k4] =
                    ((const float4*)(outh + ((size_t)(bp + row) * HLEN + t) * HDIM))[k4];
                ((float4*)&str[row][0])[k4] =
                    ((const float4*)(rg + (size_t)(bp + row) * HDIM))[k4];
            }
            __syncthreads();
            if (r8 < 6) {
                const float4* wrow = (const float4*)&wmat[r8][0] + kq * 32;
                const float4* src = (const float4*)((r8 < 2) ? &stq[b3][0] : &str[b3][0]) + kq * 32;
                float acc = 0.f;
#pragma unroll 8
                for (int k = 0; k < 32; k++) {
                    float4 a = wrow[k], bb = src[k];
                    acc += a.x * bb.x + a.y * bb.y + a.z * bb.z + a.w * bb.w;
                }
                gsa[r8 + 8 * kq][b3] = acc;
            }
            __syncthreads();
            if (tid < 16) {
                int bb3 = tid & 7, uu = tid >> 3;
                float aq = 0.f, ar = 0.f, at = 0.f;
#pragma unroll 4
                for (int k = 0; k < 4; k++) {
                    aq += gsa[uu + 8 * k][bb3];
                    ar += gsa[2 + uu + 8 * k][bb3];
                    at += gsa[4 + uu + 8 * k][bb3];
                }
                int b = bp + bb3;
                a2g[(size_t)b * HDIM + u0 + uu] = (t == 0) ? aq : (aq + ar);
                ttg[(size_t)b * HDIM + u0 + uu] = (t == 0) ? 0.0f : tanhfast(at);
            }
            __syncthreads();
        }
        gbar(cnt, gen);

        // ---- phase B: s[b][p] = sum_h wv[h]*tanh(a1+a2)
        {
            int b = bk & 63, pc = bk >> 6;
            int p = tid & 31, hc = tid >> 5;
            const float* a1p = a1b + (size_t)b * HDIM * PLEN + pc * 32 + p;
            const float* a2p = a2g + (size_t)b * HDIM;
            float s = 0.f;
            for (int h = hc * 64; h < hc * 64 + 64; h++) {
                s += wvs[h] * tanhfast(a1p[(size_t)h * PLEN] + a2p[h]);
            }
            sred[hc][p] = s;
            __syncthreads();
            if (tid < 32) {
                float tot = 0.f;
#pragma unroll 8
                for (int j = 0; j < 8; j++) tot += sred[j][tid];
                sgb[(size_t)b * PLEN + pc * 32 + tid] = tot;
            }
        }
        gbar(cnt, gen);

        // ---- phase C: softmax over p + r update
        {
            int b = bk & 63, uc = bk >> 6;
            if (tid < 128) scb[tid] = sgb[(size_t)b * PLEN + tid];
            __syncthreads();
            if (tid < 64) {
                float v0 = scb[tid], v1 = scb[tid + 64];
                float m = fmaxf(v0, v1);
                for (int o = 32; o; o >>= 1) m = fmaxf(m, __shfl_xor(m, o));
                float e0 = __expf(v0 - m), e1 = __expf(v1 - m);
                float ss = e0 + e1;
                for (int o = 32; o; o >>= 1) ss += __shfl_xor(ss, o);
                float inv = 1.0f / ss;
                scb[tid] = e0 * inv;
                scb[tid + 64] = e1 * inv;
            }
            __syncthreads();
            int ul = tid & 127, ph = tid >> 7;
            const float* opb = outp + ((size_t)b * PLEN + ph * 64) * HDIM + uc * 128 + ul;
            float acc = 0.f;
#pragma unroll 4
            for (int pp = 0; pp < 64; pp++)
                acc += scb[ph * 64 + pp] * opb[(size_t)pp * HDIM];
            rred[ph][ul] = acc;
            __syncthreads();
            if (tid < 128) {
                int u = uc * 128 + tid;
                rg[(size_t)b * HDIM + u] = rred[0][tid] + rred[1][tid]
                                         + ttg[(size_t)b * HDIM + u];
            }
        }
        gbar(cnt, gen);
    }
}

// ---------------------------------------------------------------------------
// final: rep = tanh(r.fc1^T + b1 + hn.fc2^T + b2); out = rep.fc3^T + b3
__global__ __launch_bounds__(256) void final_kernel(
    const float* __restrict__ r, const float* __restrict__ outh,
    const float* __restrict__ fc1w, const float* __restrict__ fc1b,
    const float* __restrict__ fc2w, const float* __restrict__ fc2b,
    const float* __restrict__ fc3w, const float* __restrict__ fc3b,
    float* __restrict__ out)
{
    int b = blockIdx.x, tid = threadIdx.x;
    __shared__ float rs[HDIM], hs[HDIM], rep[HDIM], red[256];
    for (int i = tid; i < 128; i += 256) {
        ((float4*)rs)[i] = ((const float4*)(r + (size_t)b * HDIM))[i];
        ((float4*)hs)[i] = ((const float4*)(outh + ((size_t)(b * HLEN + HLEN - 1)) * HDIM))[i];
    }
    __syncthreads();
    for (int u = tid; u < HDIM; u += 256) {
        const float4* w1 = (const float4*)(fc1w + (size_t)u * HDIM);
        const float4* w2 = (const float4*)(fc2w + (size_t)u * HDIM);
        float a = 0.f, bacc = 0.f;
        for (int k = 0; k < 128; k++) {
            float4 rv = ((float4*)rs)[k], hv = ((float4*)hs)[k];
            float4 x = w1[k]; a    += rv.x * x.x + rv.y * x.y + rv.z * x.z + rv.w * x.w;
            float4 y = w2[k]; bacc += hv.x * y.x + hv.y * y.y + hv.z * y.z + hv.w * y.w;
        }
        rep[u] = tanhfast(a + fc1b[u] + bacc + fc2b[u]);
    }
    __syncthreads();
    for (int cix = 0; cix < NCLS; cix++) {
        red[tid] = rep[tid] * fc3w[(size_t)cix * HDIM + tid]
                 + rep[tid + 256] * fc3w[(size_t)cix * HDIM + tid + 256];
        __syncthreads();
        for (int off = 128; off; off >>= 1) {
            if (tid < off) red[tid] += red[tid + off];
            __syncthreads();
        }
        if (tid == 0) out[b * NCLS + cix] = red[0] + fc3b[cix];
        __syncthreads();
    }
}

// ---------------------------------------------------------------------------
extern "C" void kernel_launch(void* const* d_in, const int* in_sizes, int n_in,
                              void* d_out, int out_size, void* d_ws, size_t ws_size,
                              hipStream_t stream)
{
    const int*   premise = (const int*)d_in[0];
    const int*   hyp     = (const int*)d_in[1];
    const float* emb     = (const float*)d_in[2];
    const float* Wih1    = (const float*)d_in[3];
    const float* Whh1    = (const float*)d_in[4];
    const float* bih1    = (const float*)d_in[5];
    const float* bhh1    = (const float*)d_in[6];
    const float* Wih2    = (const float*)d_in[7];
    const float* Whh2    = (const float*)d_in[8];
    const float* bih2    = (const float*)d_in[9];
    const float* bhh2    = (const float*)d_in[10];
    const float* Wy      = (const float*)d_in[11];
    const float* Wh      = (const float*)d_in[12];
    const float* Wr      = (const float*)d_in[13];
    const float* Wt      = (const float*)d_in[14];
    const float* wv      = (const float*)d_in[15];
    const float* fc1w    = (const float*)d_in[16];
    const float* fc1b    = (const float*)d_in[17];
    const float* fc2w    = (const float*)d_in[18];
    const float* fc2b    = (const float*)d_in[19];
    const float* fc3w    = (const float*)d_in[20];
    const float* fc3b    = (const float*)d_in[21];
    float* out = (float*)d_out;

    float* ws = (float*)d_ws;
    size_t off = 0;
    float* xp    = ws + off; off += (size_t)BSZ * PLEN * G4;
    float* xh    = ws + off; off += (size_t)BSZ * HLEN * G4;
    float* outp  = ws + off; off += (size_t)BSZ * PLEN * HDIM;
    float* outhp = ws + off; off += (size_t)BSZ * HLEN * HDIM;
    float* a1b   = ws + off; off += (size_t)BSZ * HDIM * PLEN;
    float* hAb   = ws + off; off += BSZ * HDIM;
    float* hBb   = ws + off; off += BSZ * HDIM;
    float* a2g   = ws + off; off += BSZ * HDIM;
    float* ttg   = ws + off; off += BSZ * HDIM;
    float* sgb   = ws + off; off += BSZ * PLEN;
    float* rgb   = ws + off; off += BSZ * HDIM;
    unsigned* bar = (unsigned*)(ws + off); off += 64;
    if (ws_size < off * sizeof(float)) return;

    // re-init barrier counters on every call (workspace is poisoned each launch)
    bar_init<<<dim3(1), dim3(64), 0, stream>>>(bar);

    // input projections (biases folded in)
    proj_kernel<<<dim3(BSZ * PLEN / 16, G4 / 32), dim3(256), 0, stream>>>(
        premise, emb, Wih1, bih1, bhh1, xp);
    proj_kernel<<<dim3(BSZ * HLEN / 16, G4 / 32), dim3(256), 0, stream>>>(
        hyp, emb, Wih2, bih2, bhh2, xh);

    // both LSTMs in one persistent kernel with software grid barrier
    lstm_coop<<<dim3(NBLK), dim3(256), 0, stream>>>(
        xp, xh, Whh1, Whh2, outp, outhp, hAb, hBb, bar);

    // a1 = einsum('hj,bpj->bhp', Wy, outp)
    a1_kernel<<<dim3(BSZ, HDIM / 16, PLEN / 16), dim3(256), 0, stream>>>(Wy, outp, a1b);

    // word-by-word attention recurrence, persistent with software grid barrier
    att_coop<<<dim3(NBLK), dim3(256), 0, stream>>>(
        outhp, rgb, a1b, a2g, ttg, sgb, outp, Wh, Wr, Wt, wv, bar);

    // final classifier
    final_kernel<<<dim3(BSZ), dim3(256), 0, stream>>>(
        rgb, outhp, fc1w, fc1b, fc2w, fc2b, fc3w, fc3b, out);
}

// Round 4
// 6179.863 us; speedup vs baseline: 3.5594x; 2.7020x over previous
//
#include <hip/hip_runtime.h>
#include <math.h>

#define BSZ 64
#define PLEN 128
#define HLEN 64
#define EDIM 300
#define HDIM 512
#define G4 2048   // 4*HDIM
#define NCLS 3

__device__ __forceinline__ float sigf(float x) { return 1.0f / (1.0f + __expf(-x)); }
__device__ __forceinline__ float tanhfast(float x) { return 1.0f - 2.0f / (__expf(2.0f * x) + 1.0f); }

// relaxed agent-scope atomic helpers: LLC-coherent, no L2 flush/invalidate
__device__ __forceinline__ unsigned long long aload64(const unsigned long long* p) {
    return __hip_atomic_load(p, __ATOMIC_RELAXED, __HIP_MEMORY_SCOPE_AGENT);
}
__device__ __forceinline__ void astore64(unsigned long long* p, unsigned long long v) {
    __hip_atomic_store(p, v, __ATOMIC_RELAXED, __HIP_MEMORY_SCOPE_AGENT);
}

__global__ __launch_bounds__(256) void flag_init(unsigned* f) {
    f[blockIdx.x * 256 + threadIdx.x] = 0u;
}

// ---------------------------------------------------------------------------
// input projection GEMM: out[m][row] = emb[toks[m]] . Wih[row] + bih[row]+bhh[row]
__global__ __launch_bounds__(256) void proj_kernel(
    const int* __restrict__ toks, const float* __restrict__ emb,
    const float* __restrict__ Wih, const float* __restrict__ bih,
    const float* __restrict__ bhh, float* __restrict__ out)
{
    __shared__ float es[16][EDIM];
    __shared__ float wsh[32][EDIM];
    int m0 = blockIdx.x * 16, r0 = blockIdx.y * 32;
    int tid = threadIdx.x;
    for (int i = tid; i < 16 * 75; i += 256) {
        int tk = i / 75, k4 = i % 75;
        ((float4*)&es[tk][0])[k4] = ((const float4*)(emb + (size_t)toks[m0 + tk] * EDIM))[k4];
    }
    for (int i = tid; i < 32 * 75; i += 256) {
        int r = i / 75, k4 = i % 75;
        ((float4*)&wsh[r][0])[k4] = ((const float4*)(Wih + (size_t)(r0 + r) * EDIM))[k4];
    }
    __syncthreads();
    int tx = tid & 31, ty = tid >> 5;
    const float4* w4 = (const float4*)&wsh[tx][0];
    const float4* e0 = (const float4*)&es[ty][0];
    const float4* e1 = (const float4*)&es[ty + 8][0];
    float a0 = 0.f, a1 = 0.f;
#pragma unroll 5
    for (int k = 0; k < 75; k++) {
        float4 w = w4[k];
        float4 x = e0[k]; a0 += x.x * w.x + x.y * w.y + x.z * w.z + x.w * w.w;
        float4 y = e1[k]; a1 += y.x * w.x + y.y * w.y + y.z * w.z + y.w * w.w;
    }
    float bsum = bih[r0 + tx] + bhh[r0 + tx];
    out[(size_t)(m0 + ty) * G4 + r0 + tx]     = a0 + bsum;
    out[(size_t)(m0 + ty + 8) * G4 + r0 + tx] = a1 + bsum;
}

// ---------------------------------------------------------------------------
// persistent LSTM, flag-synced within batch-groups. 256 blocks x 256 threads.
// block = (ug 0..31, bg 0..7): units u0..u0+15, batches b0..b0+7.
// 64 gate-row weights live in VGPRs (thread (r,c): row r chunk c of 128).
__global__ __launch_bounds__(256, 1) void lstm_coop(
    const float* __restrict__ xp, const float* __restrict__ xh,
    const float* __restrict__ Whh1, const float* __restrict__ Whh2,
    float* __restrict__ outp, float* __restrict__ outh,
    float* __restrict__ hA, float* __restrict__ hB,
    unsigned* __restrict__ flags)
{
    const int tid = threadIdx.x;
    const int ug = blockIdx.x & 31;
    const int bg = blockIdx.x >> 5;
    const int u0 = ug * 16, b0 = bg * 8;
    const int r = tid >> 2, c = tid & 3;   // r 0..63 = g*16+uu
    const int g = r >> 4, uur = r & 15;

    __shared__ float hst[8][516];
    __shared__ float gsm[64][9];

    float4 w[32];
    {
        const float4* src = (const float4*)(Whh1 + ((size_t)(g * HDIM + u0 + uur)) * HDIM) + c * 32;
#pragma unroll
        for (int k = 0; k < 32; k++) w[k] = src[k];
    }
    float creg = 0.0f;                       // cell state, thread-private (tid<128)
    const int bbc = tid >> 4, uuc = tid & 15;
    unsigned* myflags = flags + bg * 192;

    for (int t = 0; t < PLEN + HLEN; t++) {
        const int layer2 = (t >= PLEN) ? 1 : 0;
        const int tloc = layer2 ? t - PLEN : t;
        const int T = layer2 ? HLEN : PLEN;
        const float* xproj = layer2 ? xh : xp;
        float* outseq = layer2 ? outh : outp;
        float* hwr = (t & 1) ? hB : hA;
        const float* hrd = (t & 1) ? hA : hB;

        if (t == PLEN) {   // reload layer-2 weights into VGPRs (uniform)
            const float4* src = (const float4*)(Whh2 + ((size_t)(g * HDIM + u0 + uur)) * HDIM) + c * 32;
#pragma unroll
            for (int k = 0; k < 32; k++) w[k] = src[k];
        }
        const bool have_h = (tloc != 0);
        if (have_h) {
            // wait: all 32 u-groups of this b-group stored h_{t-1}
            if (tid == 0) {
                while (__hip_atomic_load(&myflags[t - 1], __ATOMIC_RELAXED,
                                         __HIP_MEMORY_SCOPE_AGENT) != 32u)
                    __builtin_amdgcn_s_sleep(1);
            }
            __syncthreads();
            __asm__ volatile("" ::: "memory");
            // stage h_{t-1} (8 batches x 512) via LLC-coherent u64 loads
            const unsigned long long* hs64 =
                (const unsigned long long*)(hrd) + (size_t)b0 * 256;
#pragma unroll
            for (int i = 0; i < 8; i++) {
                int idx = tid + i * 256;
                int bb = idx >> 8, j = idx & 255;
                unsigned long long v = aload64(hs64 + bb * 256 + j);
                *(unsigned long long*)&hst[bb][j * 2] = v;
            }
            __syncthreads();
            // GEMV: gate row r, chunk c (weights in VGPRs, h broadcast from LDS)
#pragma unroll 1
            for (int bb = 0; bb < 8; bb++) {
                const float4* hv = (const float4*)&hst[bb][0] + c * 32;
                float ax = 0.f, ay = 0.f, az = 0.f, aw = 0.f;
#pragma unroll
                for (int k = 0; k < 32; k++) {
                    float4 a = w[k], x = hv[k];
                    ax += a.x * x.x; ay += a.y * x.y; az += a.z * x.z; aw += a.w * x.w;
                }
                float acc = (ax + ay) + (az + aw);
                acc += __shfl_xor(acc, 1);
                acc += __shfl_xor(acc, 2);
                if (c == 0) gsm[r][bb] = acc;
            }
        }
        __syncthreads();
        // cell update: thread (bb, uu), tid<128
        if (tid < 128) {
            const int b = b0 + bbc;
            size_t xb = ((size_t)b * T + tloc) * G4 + u0 + uuc;
            float gi = xproj[xb], gf = xproj[xb + 512];
            float gg = xproj[xb + 1024], go = xproj[xb + 1536];
            if (have_h) {
                gi += gsm[uuc][bbc];
                gf += gsm[16 + uuc][bbc];
                gg += gsm[32 + uuc][bbc];
                go += gsm[48 + uuc][bbc];
            }
            float cn = sigf(gf) * creg + sigf(gi) * tanhfast(gg);
            float hn = sigf(go) * tanhfast(cn);
            creg = cn;
            outseq[((size_t)b * T + tloc) * HDIM + u0 + uuc] = hn;
            float pr = __shfl_xor(hn, 1);
            if ((uuc & 1) == 0) {
                float2 v2 = make_float2(hn, pr);
                astore64((unsigned long long*)(hwr + (size_t)b * HDIM + u0 + uuc),
                         *(unsigned long long*)&v2);
            }
        }
        __asm__ volatile("" ::: "memory");
        __builtin_amdgcn_s_waitcnt(0);   // h stores complete at LLC
        __syncthreads();
        if (tid == 0)
            __hip_atomic_fetch_add(&myflags[t], 1u, __ATOMIC_RELAXED,
                                   __HIP_MEMORY_SCOPE_AGENT);
    }
}

// ---------------------------------------------------------------------------
// a1[b][h][p] = sum_j Wy[h][j] * outp[b][p][j]
__global__ __launch_bounds__(256) void a1_kernel(
    const float* __restrict__ Wy, const float* __restrict__ outp,
    float* __restrict__ a1)
{
    __shared__ float os[16][260];
    __shared__ float wsh[16][260];
    int b = blockIdx.x, h0 = blockIdx.y * 16, p0 = blockIdx.z * 16;
    int tid = threadIdx.x, tx = tid & 15, ty = tid >> 4;
    float acc = 0.f;
    for (int kc = 0; kc < 2; kc++) {
        __syncthreads();
        for (int i = tid; i < 16 * 64; i += 256) {
            int row = i >> 6, k4 = i & 63;
            ((float4*)&os[row][0])[k4] =
                ((const float4*)(outp + (size_t)(b * PLEN + p0 + row) * HDIM + kc * 256))[k4];
            ((float4*)&wsh[row][0])[k4] =
                ((const float4*)(Wy + (size_t)(h0 + row) * HDIM + kc * 256))[k4];
        }
        __syncthreads();
        const float4* ov = (const float4*)&os[tx][0];
        const float4* wv4 = (const float4*)&wsh[ty][0];
#pragma unroll 8
        for (int k = 0; k < 64; k++) {
            float4 a = ov[k], w = wv4[k];
            acc += a.x * w.x + a.y * w.y + a.z * w.z + a.w * w.w;
        }
    }
    a1[((size_t)b * HDIM + h0 + ty) * PLEN + p0 + tx] = acc;
}

// ---------------------------------------------------------------------------
// persistent attention, flag-synced within batch-groups. 256 blocks x 256 thr.
// block = (ug, bg): 16 units, 8 batches, 4 premise positions (p-slice).
// 48 weight rows (Wh/Wr/Wt x 16 units) in VGPRs of threads r<48.
__global__ __launch_bounds__(256, 1) void att_coop(
    const float* __restrict__ outh, const float* __restrict__ a1b,
    const float* __restrict__ outp,
    const float* __restrict__ Wh, const float* __restrict__ Wr,
    const float* __restrict__ Wt, const float* __restrict__ wv,
    float* __restrict__ a2buf, float* __restrict__ sbuf,
    float* __restrict__ rA, float* __restrict__ rB,
    unsigned* __restrict__ flags)
{
    const int tid = threadIdx.x;
    const int ug = blockIdx.x & 31;
    const int bg = blockIdx.x >> 5;
    const int u0 = ug * 16, b0 = bg * 8;
    const int r = tid >> 2, c = tid & 3;   // r<48: m = r>>4 (0:Wh 1:Wr 2:Wt), uu = r&15
    const int m = r >> 4, uur = r & 15;

    __shared__ float qst[8][516];
    __shared__ float rst[8][516];
    __shared__ float a2st[8][516];
    __shared__ float scst[8][132];
    __shared__ float dsm[48][9];
    __shared__ float tts[16][9];
    __shared__ float wvs[512];

    float4 w[32];
    if (r < 48) {
        const float* W = (m == 0) ? Wh : ((m == 1) ? Wr : Wt);
        const float4* src = (const float4*)(W + (size_t)(u0 + uur) * HDIM) + c * 32;
#pragma unroll
        for (int k = 0; k < 32; k++) w[k] = src[k];
    }
    for (int i = tid; i < 128; i += 256)
        ((float4*)wvs)[i] = ((const float4*)wv)[i];

    unsigned* fA = flags + 1536 + bg * 64;
    unsigned* fB = flags + 1536 + 512 + bg * 64;
    unsigned* fC = flags + 1536 + 1024 + bg * 64;
    const int bbc = tid >> 4, uuc = tid & 15;

    for (int t = 0; t < HLEN; t++) {
        float* rwr = (t & 1) ? rB : rA;
        const float* rrd = (t & 1) ? rA : rB;

        // ---- phase A: a2 = q.Wh + r.Wr ; tt = tanh(r.Wt)
        if (t > 0 && tid == 0) {
            while (__hip_atomic_load(&fC[t - 1], __ATOMIC_RELAXED,
                                     __HIP_MEMORY_SCOPE_AGENT) != 32u)
                __builtin_amdgcn_s_sleep(1);
        }
        __syncthreads();
        __asm__ volatile("" ::: "memory");
        for (int i = tid; i < 8 * 128; i += 256) {
            int bb = i >> 7, k4 = i & 127;
            ((float4*)&qst[bb][0])[k4] =
                ((const float4*)(outh + ((size_t)(b0 + bb) * HLEN + t) * HDIM))[k4];
        }
        if (t > 0) {
            const unsigned long long* rs64 =
                (const unsigned long long*)(rrd) + (size_t)b0 * 256;
#pragma unroll
            for (int i = 0; i < 8; i++) {
                int idx = tid + i * 256;
                int bb = idx >> 8, j = idx & 255;
                *(unsigned long long*)&rst[bb][j * 2] = aload64(rs64 + bb * 256 + j);
            }
        }
        __syncthreads();
        if (r < 48 && (t > 0 || m == 0)) {
#pragma unroll 1
            for (int bb = 0; bb < 8; bb++) {
                const float4* sv = (const float4*)((m == 0) ? &qst[bb][0] : &rst[bb][0]) + c * 32;
                float ax = 0.f, ay = 0.f, az = 0.f, aw = 0.f;
#pragma unroll
                for (int k = 0; k < 32; k++) {
                    float4 a = w[k], x = sv[k];
                    ax += a.x * x.x; ay += a.y * x.y; az += a.z * x.z; aw += a.w * x.w;
                }
                float acc = (ax + ay) + (az + aw);
                acc += __shfl_xor(acc, 1);
                acc += __shfl_xor(acc, 2);
                if (c == 0) dsm[r][bb] = acc;
            }
        }
        __syncthreads();
        if (tid < 128) {
            float aq = dsm[uuc][bbc];
            float ar = (t > 0) ? dsm[16 + uuc][bbc] : 0.0f;
            float at = (t > 0) ? dsm[32 + uuc][bbc] : 0.0f;
            float a2v = aq + ar;
            tts[uuc][bbc] = (t > 0) ? tanhfast(at) : 0.0f;
            float pr = __shfl_xor(a2v, 1);
            if ((uuc & 1) == 0) {
                float2 v2 = make_float2(a2v, pr);
                astore64((unsigned long long*)(a2buf + (size_t)(b0 + bbc) * HDIM + u0 + uuc),
                         *(unsigned long long*)&v2);
            }
        }
        __asm__ volatile("" ::: "memory");
        __builtin_amdgcn_s_waitcnt(0);
        __syncthreads();
        if (tid == 0)
            __hip_atomic_fetch_add(&fA[t], 1u, __ATOMIC_RELAXED, __HIP_MEMORY_SCOPE_AGENT);

        // ---- phase B: s[b][p-slice] = sum_h wv[h]*tanh(a1 + a2)
        if (tid == 0) {
            while (__hip_atomic_load(&fA[t], __ATOMIC_RELAXED,
                                     __HIP_MEMORY_SCOPE_AGENT) != 32u)
                __builtin_amdgcn_s_sleep(1);
        }
        __syncthreads();
        __asm__ volatile("" ::: "memory");
        {
            const unsigned long long* a64 =
                (const unsigned long long*)(a2buf) + (size_t)b0 * 256;
#pragma unroll
            for (int i = 0; i < 8; i++) {
                int idx = tid + i * 256;
                int bb = idx >> 8, j = idx & 255;
                *(unsigned long long*)&a2st[bb][j * 2] = aload64(a64 + bb * 256 + j);
            }
        }
        __syncthreads();
        {
            const int bb = tid >> 5, hs = tid & 31;
            const int p0 = ug * 4;
            float sx = 0.f, sy = 0.f, sz = 0.f, sw = 0.f;
            const float* a1p = a1b + ((size_t)(b0 + bb) * HDIM + hs * 16) * PLEN + p0;
#pragma unroll 4
            for (int j = 0; j < 16; j++) {
                int h = hs * 16 + j;
                float4 av = *(const float4*)(a1p + (size_t)j * PLEN);
                float wvh = wvs[h];
                float a2v = a2st[bb][h];
                sx += wvh * tanhfast(av.x + a2v);
                sy += wvh * tanhfast(av.y + a2v);
                sz += wvh * tanhfast(av.z + a2v);
                sw += wvh * tanhfast(av.w + a2v);
            }
#pragma unroll
            for (int o = 1; o < 32; o <<= 1) {
                sx += __shfl_xor(sx, o);
                sy += __shfl_xor(sy, o);
                sz += __shfl_xor(sz, o);
                sw += __shfl_xor(sw, o);
            }
            if (hs == 0) {
                float2 v0 = make_float2(sx, sy), v1 = make_float2(sz, sw);
                unsigned long long* dst =
                    (unsigned long long*)(sbuf + (size_t)(b0 + bb) * PLEN + p0);
                astore64(dst, *(unsigned long long*)&v0);
                astore64(dst + 1, *(unsigned long long*)&v1);
            }
        }
        __asm__ volatile("" ::: "memory");
        __builtin_amdgcn_s_waitcnt(0);
        __syncthreads();
        if (tid == 0)
            __hip_atomic_fetch_add(&fB[t], 1u, __ATOMIC_RELAXED, __HIP_MEMORY_SCOPE_AGENT);

        // ---- phase C: softmax over p (redundant per block) + r update
        if (tid == 0) {
            while (__hip_atomic_load(&fB[t], __ATOMIC_RELAXED,
                                     __HIP_MEMORY_SCOPE_AGENT) != 32u)
                __builtin_amdgcn_s_sleep(1);
        }
        __syncthreads();
        __asm__ volatile("" ::: "memory");
        {
            const unsigned long long* s64 =
                (const unsigned long long*)(sbuf) + (size_t)b0 * 64;
#pragma unroll
            for (int i = 0; i < 2; i++) {
                int idx = tid + i * 256;
                int bb = idx >> 6, j = idx & 63;
                *(unsigned long long*)&scst[bb][j * 2] = aload64(s64 + bb * 64 + j);
            }
        }
        __syncthreads();
        {
            const int bb = tid >> 5, j = tid & 31;
            float4 v = *(float4*)&scst[bb][j * 4];
            float mx = fmaxf(fmaxf(v.x, v.y), fmaxf(v.z, v.w));
#pragma unroll
            for (int o = 1; o < 32; o <<= 1) mx = fmaxf(mx, __shfl_xor(mx, o));
            float ex = __expf(v.x - mx), ey = __expf(v.y - mx);
            float ez = __expf(v.z - mx), ew = __expf(v.w - mx);
            float ssum = (ex + ey) + (ez + ew);
#pragma unroll
            for (int o = 1; o < 32; o <<= 1) ssum += __shfl_xor(ssum, o);
            float inv = 1.0f / ssum;
            float4 sc4 = make_float4(ex * inv, ey * inv, ez * inv, ew * inv);
            *(float4*)&scst[bb][j * 4] = sc4;
        }
        __syncthreads();
        if (tid < 128) {
            float acc = tts[uuc][bbc];
            const float* opb = outp + (size_t)(b0 + bbc) * PLEN * HDIM + u0 + uuc;
#pragma unroll 4
            for (int p = 0; p < PLEN; p++)
                acc += scst[bbc][p] * opb[(size_t)p * HDIM];
            float pr = __shfl_xor(acc, 1);
            if ((uuc & 1) == 0) {
                float2 v2 = make_float2(acc, pr);
                astore64((unsigned long long*)(rwr + (size_t)(b0 + bbc) * HDIM + u0 + uuc),
                         *(unsigned long long*)&v2);
            }
        }
        __asm__ volatile("" ::: "memory");
        __builtin_amdgcn_s_waitcnt(0);
        __syncthreads();
        if (tid == 0)
            __hip_atomic_fetch_add(&fC[t], 1u, __ATOMIC_RELAXED, __HIP_MEMORY_SCOPE_AGENT);
    }
}

// ---------------------------------------------------------------------------
// final: rep = tanh(r.fc1^T + b1 + hn.fc2^T + b2); out = rep.fc3^T + b3
__global__ __launch_bounds__(256) void final_kernel(
    const float* __restrict__ r, const float* __restrict__ outh,
    const float* __restrict__ fc1w, const float* __restrict__ fc1b,
    const float* __restrict__ fc2w, const float* __restrict__ fc2b,
    const float* __restrict__ fc3w, const float* __restrict__ fc3b,
    float* __restrict__ out)
{
    int b = blockIdx.x, tid = threadIdx.x;
    __shared__ float rs[HDIM], hs[HDIM], rep[HDIM], red[256];
    for (int i = tid; i < 128; i += 256) {
        ((float4*)rs)[i] = ((const float4*)(r + (size_t)b * HDIM))[i];
        ((float4*)hs)[i] = ((const float4*)(outh + ((size_t)(b * HLEN + HLEN - 1)) * HDIM))[i];
    }
    __syncthreads();
    for (int u = tid; u < HDIM; u += 256) {
        const float4* w1 = (const float4*)(fc1w + (size_t)u * HDIM);
        const float4* w2 = (const float4*)(fc2w + (size_t)u * HDIM);
        float a = 0.f, bacc = 0.f;
        for (int k = 0; k < 128; k++) {
            float4 rv = ((float4*)rs)[k], hv = ((float4*)hs)[k];
            float4 x = w1[k]; a    += rv.x * x.x + rv.y * x.y + rv.z * x.z + rv.w * x.w;
            float4 y = w2[k]; bacc += hv.x * y.x + hv.y * y.y + hv.z * y.z + hv.w * y.w;
        }
        rep[u] = tanhfast(a + fc1b[u] + bacc + fc2b[u]);
    }
    __syncthreads();
    for (int cix = 0; cix < NCLS; cix++) {
        red[tid] = rep[tid] * fc3w[(size_t)cix * HDIM + tid]
                 + rep[tid + 256] * fc3w[(size_t)cix * HDIM + tid + 256];
        __syncthreads();
        for (int off = 128; off; off >>= 1) {
            if (tid < off) red[tid] += red[tid + off];
            __syncthreads();
        }
        if (tid == 0) out[b * NCLS + cix] = red[0] + fc3b[cix];
        __syncthreads();
    }
}

// ---------------------------------------------------------------------------
extern "C" void kernel_launch(void* const* d_in, const int* in_sizes, int n_in,
                              void* d_out, int out_size, void* d_ws, size_t ws_size,
                              hipStream_t stream)
{
    const int*   premise = (const int*)d_in[0];
    const int*   hyp     = (const int*)d_in[1];
    const float* emb     = (const float*)d_in[2];
    const float* Wih1    = (const float*)d_in[3];
    const float* Whh1    = (const float*)d_in[4];
    const float* bih1    = (const float*)d_in[5];
    const float* bhh1    = (const float*)d_in[6];
    const float* Wih2    = (const float*)d_in[7];
    const float* Whh2    = (const float*)d_in[8];
    const float* bih2    = (const float*)d_in[9];
    const float* bhh2    = (const float*)d_in[10];
    const float* Wy      = (const float*)d_in[11];
    const float* Wh      = (const float*)d_in[12];
    const float* Wr      = (const float*)d_in[13];
    const float* Wt      = (const float*)d_in[14];
    const float* wv      = (const float*)d_in[15];
    const float* fc1w    = (const float*)d_in[16];
    const float* fc1b    = (const float*)d_in[17];
    const float* fc2w    = (const float*)d_in[18];
    const float* fc2b    = (const float*)d_in[19];
    const float* fc3w    = (const float*)d_in[20];
    const float* fc3b    = (const float*)d_in[21];
    float* out = (float*)d_out;

    float* ws = (float*)d_ws;
    size_t off = 0;
    float* xp    = ws + off; off += (size_t)BSZ * PLEN * G4;
    float* xh    = ws + off; off += (size_t)BSZ * HLEN * G4;
    float* outp  = ws + off; off += (size_t)BSZ * PLEN * HDIM;
    float* outhp = ws + off; off += (size_t)BSZ * HLEN * HDIM;
    float* a1b   = ws + off; off += (size_t)BSZ * HDIM * PLEN;
    float* hAb   = ws + off; off += BSZ * HDIM;
    float* hBb   = ws + off; off += BSZ * HDIM;
    float* a2buf = ws + off; off += BSZ * HDIM;
    float* rAb   = ws + off; off += BSZ * HDIM;
    float* rBb   = ws + off; off += BSZ * HDIM;
    float* sbuf  = ws + off; off += BSZ * PLEN;
    unsigned* flags = (unsigned*)(ws + off); off += 4096;
    if (ws_size < off * sizeof(float)) return;

    // zero flag counters every call (d_ws is re-poisoned before each launch)
    flag_init<<<dim3(16), dim3(256), 0, stream>>>(flags);

    // input projections (biases folded in)
    proj_kernel<<<dim3(BSZ * PLEN / 16, G4 / 32), dim3(256), 0, stream>>>(
        premise, emb, Wih1, bih1, bhh1, xp);
    proj_kernel<<<dim3(BSZ * HLEN / 16, G4 / 32), dim3(256), 0, stream>>>(
        hyp, emb, Wih2, bih2, bhh2, xh);

    // both LSTMs, persistent, per-b-group flag sync (no L2-flushing fences)
    lstm_coop<<<dim3(256), dim3(256), 0, stream>>>(
        xp, xh, Whh1, Whh2, outp, outhp, hAb, hBb, flags);

    // a1 = einsum('hj,bpj->bhp', Wy, outp)
    a1_kernel<<<dim3(BSZ, HDIM / 16, PLEN / 16), dim3(256), 0, stream>>>(Wy, outp, a1b);

    // attention recurrence, persistent, per-b-group flag sync
    att_coop<<<dim3(256), dim3(256), 0, stream>>>(
        outhp, a1b, outp, Wh, Wr, Wt, wv, a2buf, sbuf, rAb, rBb, flags);

    // final classifier: r after step 63 lives in rB (63 & 1 == 1)
    final_kernel<<<dim3(BSZ), dim3(256), 0, stream>>>(
        rBb, outhp, fc1w, fc1b, fc2w, fc2b, fc3w, fc3b, out);
}